// Round 4
// baseline (454.227 us; speedup 1.0000x reference)
//
#include <hip/hip_runtime.h>

// Problem constants (from reference): B=8192, K=512, C=16
#define B_SZ 8192
#define K_SZ 512
#define C_SZ 16

// R6: contiguous stream + reduce-scatter. R5's stream hit only ~2 TB/s
// (~131 us for 265 MB). Two fixes, applied together:
//  (a) drop the nontemporal policy -- nt takes L2/MALL out of the read
//      path; the 6.3 TB/s ceiling is measured with plain loads.
//  (b) make every VMEM instruction one contiguous 1 KB block: one wave per
//      example b streams its 32 KB slab linearly, lane l reading iv4
//      [i*64 + l] for i = 0..31. A 1 KB chunk never crosses a 2 KB row, so
//      chunk i lies wholly in row i>>1: per-lane partial sums accumulate
//      into statically-indexed acc[16] (fully unrolled), then a 4-stage
//      __shfl_xor reduce-scatter (offsets 32/16/8/4; lane bit b maps to row
//      bit b-2) delivers rowsum[r] to lane group r = lane>>2, and 2 final
//      shuffles (1,2) fold the remaining lane bits. 17 shuffles + ~70 VALU
//      per lane -- noise against the 42 us of DRAM time for 265 MB.
// run_length = rowsum, t = rowsum - 1; gather logits[b][t][c], 16-wide
// shuffle log-softmax, one atomic per block (unchanged).

typedef int iv4 __attribute__((ext_vector_type(4)));

__global__ __launch_bounds__(256) void rocloss_kernel(
    const float* __restrict__ logits,   // [B, K, C] f32
    const int*   __restrict__ target,   // [B] i32
    const int*   __restrict__ mask,     // [B, C, K] i32 (leading-ones rows)
    float*       __restrict__ out)      // [1] f32 (pre-zeroed)
{
    const int tid  = threadIdx.x;
    const int lane = tid & 63;
    const int wv   = tid >> 6;                 // wave within block, 0..3
    const int b    = blockIdx.x * 4 + wv;      // one wave per example

    // Example b's mask slab: 16 rows x 512 ints = 8192 ints = 2048 iv4 = 32KB
    const iv4* __restrict__ slab4 =
        (const iv4*)(mask + (size_t)b * (C_SZ * K_SZ));

    // ---- Stream the slab: 32 fully-contiguous 1KB instructions. ----
    // acc[r] = this lane's partial sum of row r (statically indexed).
    int acc[16];
    #pragma unroll
    for (int r = 0; r < 16; ++r) {
        const iv4 qa = slab4[(r << 7) + lane];        // ints [512r, 512r+256)
        const iv4 qb = slab4[(r << 7) + 64 + lane];   // ints [512r+256, 512r+512)
        acc[r] = (qa.x + qa.y) + (qa.z + qa.w)
               + (qb.x + qb.y) + (qb.z + qb.w);
    }

    // ---- Reduce-scatter: rowsum[r] -> lane group r (r = lane>>2). ----
    const int b8 = (lane >> 5) & 1;   // lane bit 5 <-> row bit 3
    const int b4 = (lane >> 4) & 1;   // lane bit 4 <-> row bit 2
    const int b2 = (lane >> 3) & 1;   // lane bit 3 <-> row bit 1
    const int b1 = (lane >> 2) & 1;   // lane bit 2 <-> row bit 0

    int v8[8];
    #pragma unroll
    for (int k = 0; k < 8; ++k) {
        const int send = b8 ? acc[k] : acc[k + 8];    // what partner keeps
        const int recv = __shfl_xor(send, 32);
        const int keep = b8 ? acc[k + 8] : acc[k];
        v8[k] = keep + recv;                          // row b8*8 + k
    }
    int v4[4];
    #pragma unroll
    for (int k = 0; k < 4; ++k) {
        const int send = b4 ? v8[k] : v8[k + 4];
        const int recv = __shfl_xor(send, 16);
        const int keep = b4 ? v8[k + 4] : v8[k];
        v4[k] = keep + recv;                          // row b8*8 + b4*4 + k
    }
    int v2[2];
    #pragma unroll
    for (int k = 0; k < 2; ++k) {
        const int send = b2 ? v4[k] : v4[k + 2];
        const int recv = __shfl_xor(send, 8);
        const int keep = b2 ? v4[k + 2] : v4[k];
        v2[k] = keep + recv;                          // row ... + b2*2 + k
    }
    int s;
    {
        const int send = b1 ? v2[0] : v2[1];
        const int recv = __shfl_xor(send, 4);
        const int keep = b1 ? v2[1] : v2[0];
        s = keep + recv;                              // row lane>>2, partial
    }
    // Fold the remaining lane bits (0,1): full rowsum, replicated in group.
    s += __shfl_xor(s, 1);
    s += __shfl_xor(s, 2);

    const int t = s - 1;                       // counter = run_length - 1
    const int c = lane >> 2;                   // this group's candidate

    // ---- Gather the logit at the last valid timestep: logits[b][t][c] ----
    // (4 lanes of a group hit the same address -> single request, broadcast)
    const float a = logits[((size_t)b * K_SZ + (size_t)t) * C_SZ + c];

    // ---- log-softmax across the 16 candidate groups (offsets 4..32) ----
    float m = a;
    #pragma unroll
    for (int off = 32; off >= 4; off >>= 1)
        m = fmaxf(m, __shfl_xor(m, off));
    const float e = __expf(a - m);
    float s2 = e;
    #pragma unroll
    for (int off = 32; off >= 4; off >>= 1)
        s2 += __shfl_xor(s2, off);
    const float lse = m + __logf(s2);          // logsumexp over 16 candidates

    // ---- loss_b = lse - a[target[b]]; mean over B; one atomic per block ----
    __shared__ float acc_s;
    if (tid == 0) acc_s = 0.0f;
    __syncthreads();
    if (c == target[b] && (lane & 3) == 0)
        atomicAdd(&acc_s, lse - a);            // 4 LDS atomics per block
    __syncthreads();
    if (tid == 0)
        atomicAdd(out, acc_s * (1.0f / (float)B_SZ));
}

extern "C" void kernel_launch(void* const* d_in, const int* in_sizes, int n_in,
                              void* d_out, int out_size, void* d_ws, size_t ws_size,
                              hipStream_t stream) {
    const float* logits = (const float*)d_in[0];   // [B,K,C] f32
    const int*   target = (const int*)d_in[1];     // [B] i32
    const int*   mask   = (const int*)d_in[2];     // [B,C,K] i32
    float* out = (float*)d_out;

    // d_out is poisoned with 0xAA before every launch; zero it for the atomics.
    (void)hipMemsetAsync(out, 0, sizeof(float), stream);

    // One wave per example: B/4 blocks of 256 threads = 8192 waves.
    rocloss_kernel<<<B_SZ / 4, 256, 0, stream>>>(logits, target, mask, out);
}

// Round 5
// 419.105 us; speedup vs baseline: 1.0838x; 1.0838x over previous
//
#include <hip/hip_runtime.h>

// Problem constants (from reference): B=8192, K=512, C=16
#define B_SZ 8192
#define K_SZ 512
#define C_SZ 16

// R7 = revert to R2 (the 417.9 us kernel). Session model (R3-R6 post-mortem):
// timed region = ~402 us fixed harness overhead (two 1.07 GB poison fills at
// ~161 us each, 82-83% of HBM write peak) + kernel. Measured kernel times:
//   R2 sparse search  ~16 us  (45-50 MB random 64B lines, ~3 TB/s random BW)
//   R3 4-lane probes  ~33 us  (~100 MB random lines -- traffic scales)
//   R5/R6 full stream ~51 us  (265 MB at ~5.5 TB/s streaming ceiling;
//                              contiguity/nt changes were no-ops -> at ceiling)
// The sparse search is also information-theoretically minimal at 64B line
// granularity: boundary among 512 positions = 9 bits; the final full-line
// read gives 4, so >=5 distinct lines/row. R2 touches exactly 5 (the final
// line read re-hits a probed line in L1). Hence: revert, confirm ~418 us.
//
// One thread per (b,c). Binary-search the 32 cachelines of the row for the
// last line whose first element is 1 (5 probes), then read that line and
// sum: t = 16*lmax + sum(line) - 1.
__global__ __launch_bounds__(256) void rocloss_kernel(
    const float* __restrict__ logits,   // [B, K, C] f32
    const int*   __restrict__ target,   // [B] i32
    const int*   __restrict__ mask,     // [B, C, K] i32 (leading-ones rows)
    float*       __restrict__ out)      // [1] f32 (pre-zeroed)
{
    const int gid = blockIdx.x * 256 + threadIdx.x;   // 0 .. B*C-1
    const int b = gid >> 4;      // / C_SZ
    const int c = gid & 15;      // % C_SZ

    const int* __restrict__ row = mask + (size_t)gid * K_SZ;  // gid == b*C + c

    // Find lmax = max { l in [0,32) : row[16*l] == 1 }.  row[0] == 1 is
    // guaranteed (p >= 1).  Exactly 5 iterations (span 32->16->8->4->2->1),
    // uniform across lanes.
    int lo = 0, hi = 31;
    #pragma unroll 1
    while (lo < hi) {
        int mid = (lo + hi + 1) >> 1;     // in [1,31]
        if (row[mid << 4]) lo = mid; else hi = mid - 1;
    }

    // Boundary is inside line lo: p = 16*lo + s, s = popcount of that line.
    // One 64B line read (4x int4, single L1 line), branch-free sum.
    const int4* __restrict__ line = (const int4*)(row + (lo << 4));
    int4 q0 = line[0];
    int4 q1 = line[1];
    int4 q2 = line[2];
    int4 q3 = line[3];
    int s = (q0.x + q0.y + q0.z + q0.w)
          + (q1.x + q1.y + q1.z + q1.w)
          + (q2.x + q2.y + q2.z + q2.w)
          + (q3.x + q3.y + q3.z + q3.w);
    const int t = (lo << 4) + s - 1;       // counter = run_length - 1

    // Gather the logit at the last valid timestep: logits[b][t][c]
    const float a = logits[((size_t)b * K_SZ + (size_t)t) * C_SZ + c];

    // log-softmax over the 16 candidates (c dim) via width-16 shuffles.
    float m = a;
    #pragma unroll
    for (int off = 8; off; off >>= 1)
        m = fmaxf(m, __shfl_xor(m, off, 16));
    const float e = __expf(a - m);
    float s2 = e;
    #pragma unroll
    for (int off = 8; off; off >>= 1)
        s2 += __shfl_xor(s2, off, 16);
    const float lse = m + __logf(s2);      // logsumexp of the 16 adjusted logits

    // loss_b = lse - a[target[b]]; mean over B. One atomic per block.
    __shared__ float acc;
    if (threadIdx.x == 0) acc = 0.0f;
    __syncthreads();
    const int tgt = target[b];
    if (c == tgt) {
        atomicAdd(&acc, lse - a);
    }
    __syncthreads();
    if (threadIdx.x == 0) {
        atomicAdd(out, acc * (1.0f / (float)B_SZ));
    }
}

extern "C" void kernel_launch(void* const* d_in, const int* in_sizes, int n_in,
                              void* d_out, int out_size, void* d_ws, size_t ws_size,
                              hipStream_t stream) {
    const float* logits = (const float*)d_in[0];   // [B,K,C] f32
    const int*   target = (const int*)d_in[1];     // [B] i32
    const int*   mask   = (const int*)d_in[2];     // [B,C,K] i32
    float* out = (float*)d_out;

    // d_out is poisoned with 0xAA before every launch; zero it for the atomics.
    (void)hipMemsetAsync(out, 0, sizeof(float), stream);

    const int total = B_SZ * C_SZ;                 // 131072 threads
    rocloss_kernel<<<total / 256, 256, 0, stream>>>(logits, target, mask, out);
}